// Round 3
// baseline (289.997 us; speedup 1.0000x reference)
//
#include <hip/hip_runtime.h>
#include <stdint.h>

// DCN-V2 MoE low-rank cross network, fused both layers, bf16 MFMA.
// B=16384 D=1024 R=64 E=4 L=2.
//
// R2 -> R3: 512-thread blocks (8 waves), per-wave N halved. R2 spilled
// (WRITE_SIZE +53MB scratch: VGPR capped 128 < ~150 live in Phase C) and was
// occupancy-starved (8 waves/CU). Now: per-wave acc+pipeline buffers fit 128
// VGPR honestly; 512 blocks x 8 waves = 16 waves/CU (50% occ), LDS 80KB = 2
// blocks/CU exactly.
//
// Wave roles (wid 0..7), per layer, per 32-row block:
//   Phase A: GEMM1 Y[32,272] = x_l @ W1. Wave w owns nt {2w,2w+1} (expert
//            e=w>>1, q-half h=w&1) + gate frag (redundant per wave).
//   v = tanh(Y) -> per-expert LDS slice [32][64]; wave writes its q-half.
//   barrier. Phase B: c = v @ C[e]^T; wave (e,h) computes r-half h. 8 MFMA.
//   barrier. gc = gate_e * tanh(c) -> LDS [32][256] (reuses v region).
//   barrier. Phase C: Z = gc @ W2; wave owns 8 d-tiles, 2 passes x 4.
//   epilogue: out = x0 .* (Z + bias) + x_l; layer0 result re-staged into xl.

typedef __attribute__((ext_vector_type(8))) short bf16x8;
typedef __attribute__((ext_vector_type(4))) float f32x4;

#define MFMA_BF16(a, b, c) __builtin_amdgcn_mfma_f32_16x16x32_bf16((a), (b), (c), 0, 0, 0)

static constexpr int kB = 16384, kD = 1024;
static constexpr int MTILE = 32;

// workspace layout in ushort elems
static constexpr size_t W1F_OFF = 0;                         // [L][32 kt][17 nt][64][8]
static constexpr size_t W1F_SZ  = 2ull * 32 * 17 * 64 * 8;   // 557056
static constexpr size_t W2F_OFF = W1F_OFF + W1F_SZ;          // [L][8 kt][64 nt][64][8]
static constexpr size_t W2F_SZ  = 2ull * 8 * 64 * 64 * 8;    // 524288
static constexpr size_t CF_OFF  = W2F_OFF + W2F_SZ;          // [L][E][2 kt][4 nt][64][8]

__device__ __forceinline__ unsigned short f2bf(float f) {
    uint32_t u = __builtin_bit_cast(uint32_t, f);
    u = (u + 0x7FFFu + ((u >> 16) & 1u)) >> 16;   // RNE
    return (unsigned short)u;
}
__device__ __forceinline__ float bf2f(unsigned short h) {
    uint32_t u = ((uint32_t)h) << 16;
    return __builtin_bit_cast(float, u);
}
__device__ __forceinline__ float fast_tanh(float x) {
    float e = __builtin_amdgcn_exp2f(x * 2.8853900817779268f);
    return 1.0f - 2.0f * __builtin_amdgcn_rcpf(e + 1.0f);
}
__device__ __forceinline__ float fast_exp(float x) {
    return __builtin_amdgcn_exp2f(x * 1.4426950408889634f);
}

// ---------------- weight prep: fp32 -> bf16 MFMA B-fragments ----------------
__global__ __launch_bounds__(256) void prep_weights(
    const float* __restrict__ U, const float* __restrict__ V,
    const float* __restrict__ C, const float* __restrict__ gateW,
    unsigned short* __restrict__ ws)
{
    const int id = blockIdx.x * 256 + threadIdx.x;
    const int lane = id & 63;
    const int kg = lane >> 4, c = lane & 15;
    if (id < 2 * 32 * 17 * 64) {                       // W1 fragments (V transpose: scalar)
        int t = id >> 6;
        int nt = t % 17; t /= 17;
        int kt = t & 31; int i = t >> 5;
        int col = nt * 16 + c;
        bf16x8 o;
#pragma unroll
        for (int j = 0; j < 8; ++j) {
            int k = kt * 32 + kg * 8 + j;              // k = d
            float v = 0.0f;
            if (col < 256) {
                int e = col >> 6, r = col & 63;
                v = V[((size_t)(i * 4 + e) * 1024 + k) * 64 + r];
            } else if (col < 260) {
                v = gateW[(size_t)(col - 256) * 1024 + k];
            }
            o[j] = (short)f2bf(v);
        }
        *(bf16x8*)(ws + W1F_OFF + (size_t)id * 8) = o;
    } else if (id < 2 * 32 * 17 * 64 + 2 * 8 * 64 * 64) {  // W2 fragments (r consecutive: f32x4)
        int id2 = id - 2 * 32 * 17 * 64;
        int t = id2 >> 6;
        int nt = t & 63; t >>= 6;
        int kt = t & 7;  int i = t >> 3;
        int d = nt * 16 + c;
        int k0 = kt * 32 + kg * 8;
        int e = k0 >> 6, r0 = k0 & 63;
        const float* src = U + ((size_t)(i * 4 + e) * 1024 + d) * 64 + r0;
        f32x4 u0 = *(const f32x4*)src;
        f32x4 u1 = *(const f32x4*)(src + 4);
        bf16x8 o;
        o[0] = (short)f2bf(u0[0]); o[1] = (short)f2bf(u0[1]);
        o[2] = (short)f2bf(u0[2]); o[3] = (short)f2bf(u0[3]);
        o[4] = (short)f2bf(u1[0]); o[5] = (short)f2bf(u1[1]);
        o[6] = (short)f2bf(u1[2]); o[7] = (short)f2bf(u1[3]);
        *(bf16x8*)(ws + W2F_OFF + (size_t)id2 * 8) = o;
    } else if (id < 2 * 32 * 17 * 64 + 2 * 8 * 64 * 64 + 2 * 4 * 2 * 4 * 64) {  // C frags (q consecutive)
        int id3 = id - (2 * 32 * 17 * 64 + 2 * 8 * 64 * 64);
        int t = id3 >> 6;
        int nt = t & 3; t >>= 2;
        int kt = t & 1; t >>= 1;
        int e = t & 3;  int i = t >> 2;
        int r = nt * 16 + c;
        int q0 = kt * 32 + kg * 8;
        const float* src = C + ((size_t)(i * 4 + e) * 64 + r) * 64 + q0;
        f32x4 c0 = *(const f32x4*)src;
        f32x4 c1 = *(const f32x4*)(src + 4);
        bf16x8 o;
        o[0] = (short)f2bf(c0[0]); o[1] = (short)f2bf(c0[1]);
        o[2] = (short)f2bf(c0[2]); o[3] = (short)f2bf(c0[3]);
        o[4] = (short)f2bf(c1[0]); o[5] = (short)f2bf(c1[1]);
        o[6] = (short)f2bf(c1[2]); o[7] = (short)f2bf(c1[3]);
        *(bf16x8*)(ws + CF_OFF + (size_t)id3 * 8) = o;
    }
}

// ---------------- fused main kernel (512 threads, 8 waves) ----------------
__global__ __launch_bounds__(512, 4) void dcn_main(
    const float* __restrict__ x, const float* __restrict__ bias,
    const unsigned short* __restrict__ ws, float* __restrict__ out)
{
    __shared__ char smem[80 * 1024];    // 64K xl + 16K sh -> exactly 2 blocks/CU
    char* xl = smem;                    // x_l tile [32][1024] bf16, XOR-swizzled
    char* sh = smem + 64 * 1024;        // v slices [E][32][64] bf16, then gc [32][256]

    const unsigned short* w1f = ws + W1F_OFF;
    const unsigned short* w2f = ws + W2F_OFF;
    const unsigned short* cf  = ws + CF_OFF;

    const int tid = threadIdx.x;
    const int lane = tid & 63, wid = tid >> 6;      // wid 0..7
    const int kg = lane >> 4, lc = lane & 15;
    const int e = wid >> 1, h = wid & 1;            // expert / half roles
    const int mbase = blockIdx.x * MTILE;

    // ---- stage x -> xl (bf16, swizzled) ----
#pragma unroll
    for (int it = 0; it < 8; ++it) {
        int chunk = it * 512 + tid;                 // 8-float chunks, 32*128 total
        int row = chunk >> 7, col = (chunk & 127) * 8;
        const float* src = x + (size_t)(mbase + row) * 1024 + col;
        f32x4 v0 = *(const f32x4*)src;
        f32x4 v1 = *(const f32x4*)(src + 4);
        bf16x8 hv;
        hv[0] = (short)f2bf(v0[0]); hv[1] = (short)f2bf(v0[1]);
        hv[2] = (short)f2bf(v0[2]); hv[3] = (short)f2bf(v0[3]);
        hv[4] = (short)f2bf(v1[0]); hv[5] = (short)f2bf(v1[1]);
        hv[6] = (short)f2bf(v1[2]); hv[7] = (short)f2bf(v1[3]);
        int off = (row * 2048 + col * 2) ^ ((row & 7) << 4);
        *(bf16x8*)(xl + off) = hv;
    }
    __syncthreads();

    const f32x4 zf = {0.f, 0.f, 0.f, 0.f};

    for (int i = 0; i < 2; ++i) {
        // ---------- Phase A: GEMM1, wave owns nt {2w,2w+1} + gate ----------
        f32x4 acc1[2][2] = {{zf, zf}, {zf, zf}};
        f32x4 accg[2] = {zf, zf};
        {
            auto ldA = [&](bf16x8* a, int kt) {
#pragma unroll
                for (int mt = 0; mt < 2; ++mt) {
                    int row = mt * 16 + lc;
                    int off = (row * 2048 + (kt * 32 + kg * 8) * 2) ^ ((row & 7) << 4);
                    a[mt] = *(const bf16x8*)(xl + off);
                }
            };
            auto ldB = [&](bf16x8* b, int kt) {
                const unsigned short* wb = w1f + (size_t)(i * 32 + kt) * 17 * 512;
                b[0] = *(const bf16x8*)(wb + (2 * wid + 0) * 512 + lane * 8);
                b[1] = *(const bf16x8*)(wb + (2 * wid + 1) * 512 + lane * 8);
                b[2] = *(const bf16x8*)(wb + 16 * 512 + lane * 8);
            };
            auto fm = [&](const bf16x8* a, const bf16x8* b) {
#pragma unroll
                for (int nt = 0; nt < 2; ++nt) {
                    acc1[0][nt] = MFMA_BF16(a[0], b[nt], acc1[0][nt]);
                    acc1[1][nt] = MFMA_BF16(a[1], b[nt], acc1[1][nt]);
                }
                accg[0] = MFMA_BF16(a[0], b[2], accg[0]);
                accg[1] = MFMA_BF16(a[1], b[2], accg[1]);
            };
            bf16x8 aA[2], aB[2], bA[3], bB[3];
            ldA(aA, 0); ldB(bA, 0);
#pragma unroll
            for (int k2 = 0; k2 < 16; ++k2) {
                ldA(aB, 2 * k2 + 1); ldB(bB, 2 * k2 + 1);
                fm(aA, bA);
                if (k2 < 15) { ldA(aA, 2 * k2 + 2); ldB(bA, 2 * k2 + 2); }
                fm(aB, bB);
            }
        }

        // ---------- gate softmax (per-wave redundant; keep expert e) ----------
        float gate_val[2][4];
#pragma unroll
        for (int mt = 0; mt < 2; ++mt)
#pragma unroll
        for (int j = 0; j < 4; ++j) {
            int base = lane & 48;
            float l0 = __shfl(accg[mt][j], base + 0);
            float l1 = __shfl(accg[mt][j], base + 1);
            float l2 = __shfl(accg[mt][j], base + 2);
            float l3 = __shfl(accg[mt][j], base + 3);
            float m = fmaxf(fmaxf(l0, l1), fmaxf(l2, l3));
            float e0 = fast_exp(l0 - m), e1 = fast_exp(l1 - m);
            float e2 = fast_exp(l2 - m), e3 = fast_exp(l3 - m);
            float ge = e == 0 ? e0 : e == 1 ? e1 : e == 2 ? e2 : e3;
            gate_val[mt][j] = ge * __builtin_amdgcn_rcpf(e0 + e1 + e2 + e3);
        }

        // ---------- v = tanh(Y) -> expert slice [32][64], this wave's q-half ----------
        char* vsl = sh + e * 4096;
#pragma unroll
        for (int mt = 0; mt < 2; ++mt)
#pragma unroll
        for (int nt = 0; nt < 2; ++nt)
#pragma unroll
        for (int j = 0; j < 4; ++j) {
            int row = mt * 16 + kg * 4 + j;
            int q = h * 32 + nt * 16 + lc;
            int off = (row * 128 + q * 2) ^ ((row & 7) << 4);
            *(unsigned short*)(vsl + off) = f2bf(fast_tanh(acc1[mt][nt][j]));
        }
        __syncthreads();   // expert pair exchanged v halves

        // ---------- Phase B: c = v @ C[e]^T, wave computes r-half h ----------
        f32x4 accc[2][2] = {{zf, zf}, {zf, zf}};
        {
            bf16x8 a0[2], a1[2], cb0[2], cb1[2];
            const unsigned short* cbase = cf + (size_t)((i * 4 + e) * 2) * 4 * 512;
#pragma unroll
            for (int nt = 0; nt < 2; ++nt) {
                cb0[nt] = *(const bf16x8*)(cbase + (0 * 4 + h * 2 + nt) * 512 + lane * 8);
                cb1[nt] = *(const bf16x8*)(cbase + (1 * 4 + h * 2 + nt) * 512 + lane * 8);
            }
#pragma unroll
            for (int mt = 0; mt < 2; ++mt) {
                int row = mt * 16 + lc;
                int off0 = (row * 128 + (0 * 32 + kg * 8) * 2) ^ ((row & 7) << 4);
                int off1 = (row * 128 + (1 * 32 + kg * 8) * 2) ^ ((row & 7) << 4);
                a0[mt] = *(const bf16x8*)(vsl + off0);
                a1[mt] = *(const bf16x8*)(vsl + off1);
            }
#pragma unroll
            for (int nt = 0; nt < 2; ++nt) {
                accc[0][nt] = MFMA_BF16(a0[0], cb0[nt], accc[0][nt]);
                accc[1][nt] = MFMA_BF16(a0[1], cb0[nt], accc[1][nt]);
                accc[0][nt] = MFMA_BF16(a1[0], cb1[nt], accc[0][nt]);
                accc[1][nt] = MFMA_BF16(a1[1], cb1[nt], accc[1][nt]);
            }
        }
        __syncthreads();   // all v reads done; re-purpose sh as gc

        // ---------- gc = gate_e * tanh(c) -> sh as [32][256] bf16 swizzled ----------
#pragma unroll
        for (int mt = 0; mt < 2; ++mt)
#pragma unroll
        for (int nt = 0; nt < 2; ++nt)
#pragma unroll
        for (int j = 0; j < 4; ++j) {
            int row = mt * 16 + kg * 4 + j;
            int colg = e * 64 + h * 32 + nt * 16 + lc;
            float t = fast_tanh(accc[mt][nt][j]) * gate_val[mt][j];
            int off = (row * 512 + colg * 2) ^ ((row & 7) << 4);
            *(unsigned short*)(sh + off) = f2bf(t);
        }
        __syncthreads();

        // ---------- Phase C: Z = gc @ W2 (wave owns 8 d-tiles, 2 passes x 4) ----------
        for (int pass = 0; pass < 2; ++pass) {
            f32x4 acc2[2][4];
#pragma unroll
            for (int mt = 0; mt < 2; ++mt)
#pragma unroll
            for (int nt = 0; nt < 4; ++nt) acc2[mt][nt] = zf;

            auto ldA2 = [&](bf16x8* a, int kt) {
#pragma unroll
                for (int mt = 0; mt < 2; ++mt) {
                    int row = mt * 16 + lc;
                    int off = (row * 512 + (kt * 32 + kg * 8) * 2) ^ ((row & 7) << 4);
                    a[mt] = *(const bf16x8*)(sh + off);
                }
            };
            auto ldB2 = [&](bf16x8* b, int kt) {
                const unsigned short* w2b = w2f + (size_t)(i * 8 + kt) * 64 * 512;
#pragma unroll
                for (int nt = 0; nt < 4; ++nt)
                    b[nt] = *(const bf16x8*)(w2b + (wid * 8 + pass * 4 + nt) * 512 + lane * 8);
            };
            auto fm2 = [&](const bf16x8* a, const bf16x8* b) {
#pragma unroll
                for (int nt = 0; nt < 4; ++nt) {
                    acc2[0][nt] = MFMA_BF16(a[0], b[nt], acc2[0][nt]);
                    acc2[1][nt] = MFMA_BF16(a[1], b[nt], acc2[1][nt]);
                }
            };
            bf16x8 aA[2], aB[2], bA[4], bB[4];
            ldA2(aA, 0); ldB2(bA, 0);
#pragma unroll
            for (int k2 = 0; k2 < 4; ++k2) {
                ldA2(aB, 2 * k2 + 1); ldB2(bB, 2 * k2 + 1);
                fm2(aA, bA);
                if (k2 < 3) { ldA2(aA, 2 * k2 + 2); ldB2(bA, 2 * k2 + 2); }
                fm2(aB, bB);
            }

            // ---------- fused epilogue: out = x0 .* (Z + bias) + x_l ----------
#pragma unroll
            for (int nt = 0; nt < 4; ++nt) {
                int d = wid * 128 + pass * 64 + nt * 16 + lc;
                float bv = bias[(size_t)i * 1024 + d];
#pragma unroll
                for (int mt = 0; mt < 2; ++mt)
#pragma unroll
                for (int j = 0; j < 4; ++j) {
                    int row = mt * 16 + kg * 4 + j;
                    float z = acc2[mt][nt][j] + bv;
                    float x0v = x[(size_t)(mbase + row) * 1024 + d];
                    int xoff = (row * 2048 + d * 2) ^ ((row & 7) << 4);
                    float xlv = bf2f(*(const unsigned short*)(xl + xoff));
                    float o = x0v * z + xlv;                // x0*(Z+bias) + x_l
                    if (i == 0) {
                        *(unsigned short*)(xl + xoff) = f2bf(o);   // next layer's x_l
                    } else {
                        out[(size_t)(mbase + row) * 1024 + d] = o;
                    }
                }
            }
        }
        __syncthreads();   // xl rewritten / sh reused next layer
    }
}

extern "C" void kernel_launch(void* const* d_in, const int* in_sizes, int n_in,
                              void* d_out, int out_size, void* d_ws, size_t ws_size,
                              hipStream_t stream) {
    const float* x     = (const float*)d_in[0];
    const float* U     = (const float*)d_in[1];
    const float* V     = (const float*)d_in[2];
    const float* C     = (const float*)d_in[3];
    const float* bias  = (const float*)d_in[4];
    const float* gateW = (const float*)d_in[5];
    unsigned short* ws = (unsigned short*)d_ws;
    float* out = (float*)d_out;

    const int prep_threads = 2 * 32 * 17 * 64 + 2 * 8 * 64 * 64 + 2 * 4 * 2 * 4 * 64; // 139264
    prep_weights<<<(prep_threads + 255) / 256, 256, 0, stream>>>(U, V, C, gateW, ws);
    dcn_main<<<kB / MTILE, 512, 0, stream>>>(x, bias, ws, out);
}